// Round 4
// baseline (389.549 us; speedup 1.0000x reference)
//
#include <hip/hip_runtime.h>
#include <hip/hip_bf16.h>

#define DEVI __device__ __forceinline__
using u16 = unsigned short;
using u32 = unsigned int;

typedef __attribute__((ext_vector_type(4))) float f32x4;
typedef __attribute__((ext_vector_type(8))) __bf16 bf16x8;

constexpr int L_ = 2048;   // sequence length
// B=4, D=256, H=8, DH=32, DE=1024, M = B*L = 8192

DEVI u16 f2bf(float f){
  u32 u = __builtin_bit_cast(u32, f);
  u32 r = u + 0x7FFFu + ((u >> 16) & 1u);   // RNE
  return (u16)(r >> 16);
}
DEVI float sigm(float x){ return 1.f / (1.f + __expf(-x)); }

DEVI f32x4 mfma16(bf16x8 a, bf16x8 b, f32x4 c){
  return __builtin_amdgcn_mfma_f32_16x16x32_bf16(a, b, c, 0, 0, 0);
}

DEVI void gload16(const u16* src, u16* lds){
  __builtin_amdgcn_global_load_lds(
      (const __attribute__((address_space(1))) u32*)src,
      (__attribute__((address_space(3))) u32*)lds, 16, 0, 0);
}

// ---------- weight f32 -> bf16, transposed to [N][K] ----------
__global__ __launch_bounds__(256)
void wtrans(const float* __restrict__ W, u16* __restrict__ WT, int K, int N){
  __shared__ float tile[32][33];
  int n0 = blockIdx.x * 32, k0 = blockIdx.y * 32;
  int tx = threadIdx.x & 31, ty = threadIdx.x >> 5;
  #pragma unroll
  for (int i = 0; i < 4; ++i){ int kk = ty + i*8; tile[kk][tx] = W[(long)(k0+kk)*N + n0 + tx]; }
  __syncthreads();
  #pragma unroll
  for (int i = 0; i < 4; ++i){ int nn = ty + i*8; WT[(long)(n0+nn)*K + k0 + tx] = f2bf(tile[tx][nn]); }
}

// ---------- f32 -> bf16 elementwise (context) ----------
__global__ __launch_bounds__(256)
void cvt_bf(const float* __restrict__ in, u16* __restrict__ out){
  long i = ((long)blockIdx.x * 256 + threadIdx.x) * 4;
  float4 v = *(const float4*)(in + i);
  ushort4 o; o.x = f2bf(v.x); o.y = f2bf(v.y); o.z = f2bf(v.z); o.w = f2bf(v.w);
  *(ushort4*)(out + i) = o;
}

// ---------- fused LayerNorm(+add)+SiLU -> bf16 ----------
// MODE 0: silu(LN(x)+pos[l])   MODE 1: silu(LN(x))   MODE 2: silu(LN(x+shift[b]))
template<int MODE>
__global__ __launch_bounds__(256)
void ln_silu(const float* __restrict__ in, const float* __restrict__ add,
             const float* __restrict__ g, const float* __restrict__ bvec,
             u16* __restrict__ out){
  const int row  = blockIdx.x * 4 + (threadIdx.x >> 6);
  const int lane = threadIdx.x & 63;
  const long base = (long)row * 256 + lane * 4;
  float4 x4 = *(const float4*)(in + base);
  float v[4] = {x4.x, x4.y, x4.z, x4.w};
  if constexpr (MODE == 2){
    float4 s4 = *(const float4*)(add + (row >> 11) * 1280 + lane * 4); // t_shift
    v[0] += s4.x; v[1] += s4.y; v[2] += s4.z; v[3] += s4.w;
  }
  float s = v[0] + v[1] + v[2] + v[3];
  #pragma unroll
  for (int d = 1; d < 64; d <<= 1) s += __shfl_xor(s, d);
  const float mean = s * (1.f / 256.f);
  float q = 0.f;
  #pragma unroll
  for (int i = 0; i < 4; ++i){ float dd = v[i] - mean; q += dd * dd; }
  #pragma unroll
  for (int d = 1; d < 64; d <<= 1) q += __shfl_xor(q, d);
  const float rstd = rsqrtf(q * (1.f / 256.f) + 1e-5f);
  float4 g4 = *(const float4*)(g + lane * 4);
  float4 b4 = *(const float4*)(bvec + lane * 4);
  float gv[4] = {g4.x, g4.y, g4.z, g4.w}, bb[4] = {b4.x, b4.y, b4.z, b4.w};
  float pe[4] = {0.f, 0.f, 0.f, 0.f};
  if constexpr (MODE == 0){
    float4 pp = *(const float4*)(add + (long)(row & (L_ - 1)) * 256 + lane * 4);
    pe[0] = pp.x; pe[1] = pp.y; pe[2] = pp.z; pe[3] = pp.w;
  }
  ushort4 o;
  u16 tmp[4];
  #pragma unroll
  for (int i = 0; i < 4; ++i){
    float y = (v[i] - mean) * rstd * gv[i] + bb[i] + pe[i];
    y = y * sigm(y);
    tmp[i] = f2bf(y);
  }
  o.x = tmp[0]; o.y = tmp[1]; o.z = tmp[2]; o.w = tmp[3];
  *(ushort4*)(out + base) = o;
}

// ---------- MFMA GEMM: C = A(MxK,bf16) * BT(NxK,bf16)^T + bias, fused epilogues ----------
// EPI 0: bf16 out   1: f32 out   2: f32 out + res   3: split kv (k cols<256, v rest)
// EPI 4: FF1 gate: bf16 silu(v * sigmoid(t_scale[b][col]))
template<int EPI>
__global__ __launch_bounds__(256)
void gemm_bf(const u16* __restrict__ A, const u16* __restrict__ BT,
             const float* __restrict__ bias, const float* __restrict__ res,
             const float* __restrict__ thv,
             float* __restrict__ outF, u16* __restrict__ outB, u16* __restrict__ outB2,
             int M, int N, int K){
  __shared__ u16 As[128 * 64];
  __shared__ u16 Bs[128 * 64];
  const int t = threadIdx.x, lane = t & 63;
  const int lr = lane & 15, lg = lane >> 4;
  const int wr = ((t >> 6) >> 1) * 64, wc = ((t >> 6) & 1) * 64;
  const long bm = (long)blockIdx.x * 128, bn = (long)blockIdx.y * 128;
  const f32x4 zero = {0.f, 0.f, 0.f, 0.f};
  f32x4 acc[4][4];
  #pragma unroll
  for (int m = 0; m < 4; ++m)
    #pragma unroll
    for (int n = 0; n < 4; ++n) acc[m][n] = zero;

  for (int kt = 0; kt < K; kt += 64){
    // stage 128x64 A and B tiles; LDS linear, source pre-swizzled (XOR (row&7)<<4 on 16B col)
    #pragma unroll
    for (int i = 0; i < 4; ++i){
      int o   = t * 16 + i * 4096;       // byte offset in tile
      int row = o >> 7, cb = o & 127;
      int scb = cb ^ ((row & 7) << 4);
      gload16(&A [(bm + row) * K + kt + (scb >> 1)], &As[o >> 1]);
      gload16(&BT[(bn + row) * K + kt + (scb >> 1)], &Bs[o >> 1]);
    }
    __syncthreads();
    #pragma unroll
    for (int ks = 0; ks < 2; ++ks){
      bf16x8 av[4], bv[4];
      const int cb = (ks * 32 + lg * 8) * 2;
      #pragma unroll
      for (int m = 0; m < 4; ++m){
        int row = wr + m * 16 + lr;
        av[m] = *(const bf16x8*)((const char*)As + row * 128 + (cb ^ ((row & 7) << 4)));
      }
      #pragma unroll
      for (int n = 0; n < 4; ++n){
        int row = wc + n * 16 + lr;
        bv[n] = *(const bf16x8*)((const char*)Bs + row * 128 + (cb ^ ((row & 7) << 4)));
      }
      #pragma unroll
      for (int m = 0; m < 4; ++m)
        #pragma unroll
        for (int n = 0; n < 4; ++n)
          acc[m][n] = mfma16(av[m], bv[n], acc[m][n]);
    }
    __syncthreads();
  }
  #pragma unroll
  for (int m = 0; m < 4; ++m)
    #pragma unroll
    for (int n = 0; n < 4; ++n)
      #pragma unroll
      for (int r = 0; r < 4; ++r){
        long row = bm + wr + m * 16 + lg * 4 + r;
        long col = bn + wc + n * 16 + lr;
        float v = acc[m][n][r] + bias[col];
        if constexpr (EPI == 0){
          outB[row * N + col] = f2bf(v);
        } else if constexpr (EPI == 1){
          outF[row * N + col] = v;
        } else if constexpr (EPI == 2){
          outF[row * N + col] = v + res[row * N + col];
        } else if constexpr (EPI == 3){
          if (col < 256) outB [row * 256  + col]        = f2bf(v);
          else           outB2[row * 2048 + (col - 256)] = f2bf(v);
        } else {
          int b = (int)(row >> 11);
          float ts = thv[b * 1280 + 256 + (int)col];
          float z = v * sigm(ts);
          outB[row * N + col] = f2bf(z * sigm(z));
        }
      }
}

// ---------- V transpose: (B*L, 2048 h-major) -> VT[bh][d][m] ----------
__global__ __launch_bounds__(256)
void vtrans(const u16* __restrict__ V, u16* __restrict__ VT){
  __shared__ u16 tile[64][72];
  int m0 = blockIdx.x * 64, d0 = blockIdx.y * 64;
  int bh = blockIdx.z, b = bh >> 3, h = bh & 7;
  int t = threadIdx.x;
  int rl = t >> 3, c8 = (t & 7) * 8;
  #pragma unroll
  for (int rep = 0; rep < 2; ++rep){
    int m = rl + rep * 32;
    uint4 x = *(const uint4*)(V + ((long)(b * L_ + m0 + m)) * 2048 + h * 256 + d0 + c8);
    *(uint4*)&tile[m][c8] = x;
  }
  __syncthreads();
  u16 tmp[8] __attribute__((aligned(16)));
  #pragma unroll
  for (int rep = 0; rep < 2; ++rep){
    int d = rl + rep * 32;
    #pragma unroll
    for (int i = 0; i < 8; ++i) tmp[i] = tile[c8 + i][d];
    *(uint4*)(VT + ((long)(bh * 256 + d0 + d)) * 2048 + m0 + c8) = *(uint4*)tmp;
  }
}

// ---------- flash attention v5: 4 waves x 32q = 128q/block (one chunk), V LDS dbuf,
// K direct-from-global, P XOR-swizzled 16KB, LDS exactly 80KB -> 2 blocks/CU ----------
// anti-causal: attend m >= n. blockIdx.x = bh (XCD locality), y mirror-paired.
__global__ __launch_bounds__(256, 2)
void attn5(const u16* __restrict__ Q, const u16* __restrict__ Kb,
           const u16* __restrict__ VT, u16* __restrict__ attout){
  const int bh = blockIdx.x, b = bh >> 3, h = bh & 7;
  const int yc = blockIdx.y;
  const int chunk = (yc < 8) ? yc : 23 - yc;   // co-resident pair sums to ~34 tiles
  const int n0 = chunk * 128;
  const int t = threadIdx.x;
  const int w = t >> 6, lane = t & 63, lr = lane & 15, lg = lane >> 4;
  const int n_lo = n0 + w * 32;                // this wave's 32 queries
  const int nt = (L_ - n0) >> 6;               // 32 - 2*chunk tiles

  __shared__ u16 Vs[2][256 * 64];   // [d][m] 128B rows, XOR (d&7)<<4 byte-swizzle  (64KB)
  __shared__ u16 Ps[4][32 * 64];    // per-wave P, XOR-swizzled 128B rows           (16KB)
  u16* myP = &Ps[w][0];

  const f32x4 zero = {0.f, 0.f, 0.f, 0.f};
  constexpr float scale2 = 0.17677669529663687f * 1.4426950408889634f; // 1/sqrt(32)*log2e

  const u16* vbase = VT + (long)bh * 256 * 2048;
  const u16* kbase = Kb + (long)(b * L_) * 256 + h * 32;

  bf16x8 qf[2];
  #pragma unroll
  for (int qh = 0; qh < 2; ++qh)
    qf[qh] = *(const bf16x8*)(Q + ((long)(b * L_ + n_lo + qh * 16 + lr)) * 256 + h * 32 + lg * 8);

  f32x4 o[2][16];
  #pragma unroll
  for (int qh = 0; qh < 2; ++qh)
    #pragma unroll
    for (int c2 = 0; c2 < 16; ++c2) o[qh][c2] = zero;
  float mrun[2][4], srun[2][4];
  #pragma unroll
  for (int qh = 0; qh < 2; ++qh)
    #pragma unroll
    for (int r = 0; r < 4; ++r){ mrun[qh][r] = -1e30f; srun[qh][r] = 0.f; }

  // ---- prologue: stage V tile 0 into buffer 0 ----
  #pragma unroll
  for (int i = 0; i < 8; ++i){
    int ob = t * 16 + i * 4096;
    int d = ob >> 7, cb = ob & 127;
    int scb = cb ^ ((d & 7) << 4);
    gload16(vbase + (long)d * 2048 + n0 + (scb >> 1), &Vs[0][ob >> 1]);
  }
  __syncthreads();

  for (int tt = 0; tt < nt; ++tt){
    const int m0 = n0 + tt * 64;
    const int cur = tt & 1, nxt = cur ^ 1;

    // ---- issue next V tile's staging (in flight during compute) ----
    if (tt + 1 < nt){
      const int m1 = m0 + 64;
      #pragma unroll
      for (int i = 0; i < 8; ++i){
        int ob = t * 16 + i * 4096;
        int d = ob >> 7, cb = ob & 127;
        int scb = cb ^ ((d & 7) << 4);
        gload16(vbase + (long)d * 2048 + m1 + (scb >> 1), &Vs[nxt][ob >> 1]);
      }
    }

    // ---- compute current tile ----
    if (m0 + 64 > n_lo){
      const bool partial = (m0 < n_lo + 32);

      // K fragments direct from global (L2-resident, shared across chunks on this XCD)
      bf16x8 kf[4];
      #pragma unroll
      for (int c = 0; c < 4; ++c)
        kf[c] = *(const bf16x8*)(kbase + (long)(m0 + c * 16 + lr) * 256 + lg * 8);

      f32x4 sc[2][4];
      #pragma unroll
      for (int qh = 0; qh < 2; ++qh)
        #pragma unroll
        for (int c = 0; c < 4; ++c)
          sc[qh][c] = mfma16(qf[qh], kf[c], zero);

      // scale (log2 domain) + mask
      #pragma unroll
      for (int qh = 0; qh < 2; ++qh)
        #pragma unroll
        for (int c = 0; c < 4; ++c)
          #pragma unroll
          for (int r = 0; r < 4; ++r){
            float sv = sc[qh][c][r] * scale2;
            if (partial && (m0 + c * 16 + lr) < (n_lo + qh * 16 + lg * 4 + r)) sv = -1e30f;
            sc[qh][c][r] = sv;
          }

      // tile max per row; deferred rescale (threshold 11.5 log2 ~ e^8)
      float tmax[2][4];
      bool needl = false;
      #pragma unroll
      for (int qh = 0; qh < 2; ++qh)
        #pragma unroll
        for (int r = 0; r < 4; ++r){
          float t0 = fmaxf(fmaxf(sc[qh][0][r], sc[qh][1][r]), fmaxf(sc[qh][2][r], sc[qh][3][r]));
          #pragma unroll
          for (int d = 1; d < 16; d <<= 1) t0 = fmaxf(t0, __shfl_xor(t0, d));
          tmax[qh][r] = t0;
          needl |= (t0 > mrun[qh][r] + 11.5f);
        }
      if (__any(needl)){
        #pragma unroll
        for (int qh = 0; qh < 2; ++qh){
          float fr[4];
          #pragma unroll
          for (int r = 0; r < 4; ++r){
            float mn = fmaxf(mrun[qh][r], tmax[qh][r]);
            fr[r] = exp2f(mrun[qh][r] - mn);
            mrun[qh][r] = mn;
            srun[qh][r] *= fr[r];
          }
          f32x4 fv = {fr[0], fr[1], fr[2], fr[3]};
          #pragma unroll
          for (int c2 = 0; c2 < 16; ++c2) o[qh][c2] *= fv;
        }
      }

      // exp2 + row sums, P -> LDS (per-wave region, XOR-swizzled, no barrier)
      #pragma unroll
      for (int qh = 0; qh < 2; ++qh)
        #pragma unroll
        for (int r = 0; r < 4; ++r){
          const int prow = qh * 16 + lg * 4 + r;
          float rs = 0.f;
          #pragma unroll
          for (int c = 0; c < 4; ++c){
            float e = exp2f(sc[qh][c][r] - mrun[qh][r]);
            if (partial && mrun[qh][r] < -1e29f) e = 0.f;
            myP[prow * 64 + ((c * 16 + lr) ^ ((prow & 7) << 3))] =
                __builtin_bit_cast(u16, (__bf16)e);
            rs += e;
          }
          #pragma unroll
          for (int d = 1; d < 16; d <<= 1) rs += __shfl_xor(rs, d);
          srun[qh][r] += rs;
        }

      // ---- PV ----
      #pragma unroll
      for (int ks = 0; ks < 2; ++ks){
        bf16x8 pa[2];
        #pragma unroll
        for (int qh = 0; qh < 2; ++qh){
          const int arow = qh * 16 + lr;
          pa[qh] = *(const bf16x8*)(myP + arow * 64 + ((ks * 32 + lg * 8) ^ ((arow & 7) << 3)));
        }
        #pragma unroll
        for (int c2 = 0; c2 < 16; ++c2){
          int d = c2 * 16 + lr;
          bf16x8 vf = *(const bf16x8*)((const char*)&Vs[cur][0] + d * 128 +
                                       ((ks * 64 + lg * 16) ^ ((d & 7) << 4)));
          #pragma unroll
          for (int qh = 0; qh < 2; ++qh)
            o[qh][c2] = mfma16(pa[qh], vf, o[qh][c2]);
        }
      }
    }

    __syncthreads();   // all waves done with Vs[cur]; next V staged (vmcnt drained)
  }

  // epilogue
  #pragma unroll
  for (int qh = 0; qh < 2; ++qh)
    #pragma unroll
    for (int r = 0; r < 4; ++r){
      float inv = 1.f / srun[qh][r];
      long row = (long)(b * L_ + n_lo + qh * 16 + lg * 4 + r);
      #pragma unroll
      for (int c2 = 0; c2 < 16; ++c2)
        attout[row * 2048 + h * 256 + c2 * 16 + lr] = f2bf(o[qh][c2][r] * inv);
    }
}

// ---------- tiny t-MLP ----------
__global__ __launch_bounds__(256)
void tmlp1(const float* __restrict__ t, const float* __restrict__ W,
           const float* __restrict__ bias, float* __restrict__ u){
  __shared__ float ts[256];
  int b = blockIdx.x, j = threadIdx.x;
  ts[j] = t[b * 256 + j];
  __syncthreads();
  float acc = bias[j];
  for (int k = 0; k < 256; ++k) acc += ts[k] * W[k * 256 + j];
  u[b * 256 + j] = acc * sigm(acc);
}
__global__ __launch_bounds__(256)
void tmlp2(const float* __restrict__ u, const float* __restrict__ W,
           const float* __restrict__ bias, float* __restrict__ th){
  __shared__ float us[256];
  int b = blockIdx.y, j = blockIdx.x * 256 + threadIdx.x;
  us[threadIdx.x] = u[b * 256 + threadIdx.x];
  __syncthreads();
  float acc = bias[j];
  for (int k = 0; k < 256; ++k) acc += us[k] * W[k * 1280 + j];
  th[b * 1280 + j] = acc;
}

extern "C" void kernel_launch(void* const* d_in, const int* in_sizes, int n_in,
                              void* d_out, int out_size, void* d_ws, size_t ws_size,
                              hipStream_t stream){
  (void)in_sizes; (void)n_in; (void)out_size; (void)ws_size;
  const float* x    = (const float*)d_in[0];
  const float* ctx  = (const float*)d_in[1];
  const float* tin  = (const float*)d_in[2];
  const float* pos  = (const float*)d_in[3];
  const float* ln_g = (const float*)d_in[4];
  const float* ln_b = (const float*)d_in[5];
  const float* Wq   = (const float*)d_in[6];
  const float* bq   = (const float*)d_in[7];
  const float* Wkv1 = (const float*)d_in[8];
  const float* bkv1 = (const float*)d_in[9];
  const float* kvg  = (const float*)d_in[10];
  const float* kvb  = (const float*)d_in[11];
  const float* Wkv2 = (const float*)d_in[12];
  const float* bkv2 = (const float*)d_in[13];
  const float* Wm   = (const float*)d_in[14];
  const float* bm   = (const float*)d_in[15];
  const float* Wt1  = (const float*)d_in[16];
  const float* bt1  = (const float*)d_in[17];
  const float* Wt2  = (const float*)d_in[18];
  const float* bt2  = (const float*)d_in[19];
  const float* fg   = (const float*)d_in[20];
  const float* fb   = (const float*)d_in[21];
  const float* Wff1 = (const float*)d_in[22];
  const float* bff1 = (const float*)d_in[23];
  const float* Wff2 = (const float*)d_in[24];
  const float* bff2 = (const float*)d_in[25];

  char* ws = (char*)d_ws;
  u16*   wt_q   = (u16*)  (ws + 0);
  u16*   wt_kv1 = (u16*)  (ws + 131072);
  u16*   wt_kv2 = (u16*)  (ws + 262144);
  u16*   wt_m   = (u16*)  (ws + 1441792);
  u16*   wt_ff1 = (u16*)  (ws + 2490368);
  u16*   wt_ff2 = (u16*)  (ws + 3014656);
  u16*   ctx_bf = (u16*)  (ws + 3538944);    // later reused: ff1 input
  u16*   qin_bf = (u16*)  (ws + 7733248);    // later reused: kvln
  u16*   q_bf   = (u16*)  (ws + 11927552);
  float* kv1    = (float*)(ws + 16121856);   // later reused: x2
  u16*   k_bf   = (u16*)  (ws + 24510464);
  u16*   v_bf   = (u16*)  (ws + 28704768);   // later reused: attention out
  u16*   vT     = (u16*)  (ws + 62259200);   // later reused: gated h
  float* ub     = (float*)(ws + 95813632);
  float* th     = (float*)(ws + 95817728);

  // weight prep (bf16, transposed to [N][K])
  wtrans<<<dim3(8, 8),  256, 0, stream>>>(Wq,   wt_q,   256,  256);
  wtrans<<<dim3(8, 8),  256, 0, stream>>>(Wkv1, wt_kv1, 256,  256);
  wtrans<<<dim3(72, 8), 256, 0, stream>>>(Wkv2, wt_kv2, 256,  2304);
  wtrans<<<dim3(8, 64), 256, 0, stream>>>(Wm,   wt_m,   2048, 256);
  wtrans<<<dim3(32, 8), 256, 0, stream>>>(Wff1, wt_ff1, 256,  1024);
  wtrans<<<dim3(8, 32), 256, 0, stream>>>(Wff2, wt_ff2, 1024, 256);
  cvt_bf<<<2048, 256, 0, stream>>>(ctx, ctx_bf);

  // q = silu(LN(x)+pos) @ Wq + bq
  ln_silu<0><<<2048, 256, 0, stream>>>(x, pos, ln_g, ln_b, qin_bf);
  gemm_bf<0><<<dim3(64, 2), 256, 0, stream>>>(qin_bf, wt_q, bq, nullptr, nullptr,
                                              nullptr, q_bf, nullptr, 8192, 256, 256);
  // kv = silu(LN(ctx@Wkv1+bkv1)) @ Wkv2 + bkv2 -> K, V
  gemm_bf<1><<<dim3(64, 2), 256, 0, stream>>>(ctx_bf, wt_kv1, bkv1, nullptr, nullptr,
                                              kv1, nullptr, nullptr, 8192, 256, 256);
  ln_silu<1><<<2048, 256, 0, stream>>>(kv1, nullptr, kvg, kvb, qin_bf);
  gemm_bf<3><<<dim3(64, 18), 256, 0, stream>>>(qin_bf, wt_kv2, bkv2, nullptr, nullptr,
                                               nullptr, k_bf, v_bf, 8192, 2304, 256);
  vtrans<<<dim3(32, 4, 32), 256, 0, stream>>>(v_bf, vT);

  // attention (writes into v_bf region, reads vT/k_bf/q_bf)
  attn5<<<dim3(32, 16), 256, 0, stream>>>(q_bf, k_bf, vT, v_bf);

  // x2 = x + att @ Wm + bm
  gemm_bf<2><<<dim3(64, 2), 256, 0, stream>>>(v_bf, wt_m, bm, x, nullptr,
                                              kv1, nullptr, nullptr, 8192, 256, 2048);
  // t-MLP
  tmlp1<<<4, 256, 0, stream>>>(tin, Wt1, bt1, ub);
  tmlp2<<<dim3(5, 4), 256, 0, stream>>>(ub, Wt2, bt2, th);
  // h = silu(LN(x2+shift)); hg = silu(h@Wff1+bff1 * sigmoid(scale)); out = hg@Wff2+bff2+x2
  ln_silu<2><<<2048, 256, 0, stream>>>(kv1, th, fg, fb, ctx_bf);
  gemm_bf<4><<<dim3(64, 8), 256, 0, stream>>>(ctx_bf, wt_ff1, bff1, nullptr, th,
                                              nullptr, vT, nullptr, 8192, 1024, 256);
  gemm_bf<2><<<dim3(64, 2), 256, 0, stream>>>(vT, wt_ff2, bff2, kv1, nullptr,
                                              (float*)d_out, nullptr, nullptr, 8192, 256, 1024);
}

// Round 5
// 274.842 us; speedup vs baseline: 1.4174x; 1.4174x over previous
//
#include <hip/hip_runtime.h>
#include <hip/hip_bf16.h>

#define DEVI __device__ __forceinline__
using u16 = unsigned short;
using u32 = unsigned int;

typedef __attribute__((ext_vector_type(4))) float f32x4;
typedef __attribute__((ext_vector_type(8))) __bf16 bf16x8;

constexpr int L_ = 2048;   // sequence length
// B=4, D=256, H=8, DH=32, DE=1024, M = B*L = 8192

DEVI u16 f2bf(float f){
  u32 u = __builtin_bit_cast(u32, f);
  u32 r = u + 0x7FFFu + ((u >> 16) & 1u);   // RNE
  return (u16)(r >> 16);
}
DEVI float sigm(float x){ return 1.f / (1.f + __expf(-x)); }

DEVI f32x4 mfma16(bf16x8 a, bf16x8 b, f32x4 c){
  return __builtin_amdgcn_mfma_f32_16x16x32_bf16(a, b, c, 0, 0, 0);
}

DEVI void gload16(const u16* src, u16* lds){
  __builtin_amdgcn_global_load_lds(
      (const __attribute__((address_space(1))) u32*)src,
      (__attribute__((address_space(3))) u32*)lds, 16, 0, 0);
}

#define WAITV(N) asm volatile("s_waitcnt vmcnt(" #N ")" ::: "memory")

// ---------- weight f32 -> bf16, transposed to [N][K] ----------
__global__ __launch_bounds__(256)
void wtrans(const float* __restrict__ W, u16* __restrict__ WT, int K, int N){
  __shared__ float tile[32][33];
  int n0 = blockIdx.x * 32, k0 = blockIdx.y * 32;
  int tx = threadIdx.x & 31, ty = threadIdx.x >> 5;
  #pragma unroll
  for (int i = 0; i < 4; ++i){ int kk = ty + i*8; tile[kk][tx] = W[(long)(k0+kk)*N + n0 + tx]; }
  __syncthreads();
  #pragma unroll
  for (int i = 0; i < 4; ++i){ int nn = ty + i*8; WT[(long)(n0+nn)*K + k0 + tx] = f2bf(tile[tx][nn]); }
}

// ---------- f32 -> bf16 elementwise (context) ----------
__global__ __launch_bounds__(256)
void cvt_bf(const float* __restrict__ in, u16* __restrict__ out){
  long i = ((long)blockIdx.x * 256 + threadIdx.x) * 4;
  float4 v = *(const float4*)(in + i);
  ushort4 o; o.x = f2bf(v.x); o.y = f2bf(v.y); o.z = f2bf(v.z); o.w = f2bf(v.w);
  *(ushort4*)(out + i) = o;
}

// ---------- fused LayerNorm(+add)+SiLU -> bf16 ----------
// MODE 0: silu(LN(x)+pos[l])   MODE 1: silu(LN(x))   MODE 2: silu(LN(x+shift[b]))
template<int MODE>
__global__ __launch_bounds__(256)
void ln_silu(const float* __restrict__ in, const float* __restrict__ add,
             const float* __restrict__ g, const float* __restrict__ bvec,
             u16* __restrict__ out){
  const int row  = blockIdx.x * 4 + (threadIdx.x >> 6);
  const int lane = threadIdx.x & 63;
  const long base = (long)row * 256 + lane * 4;
  float4 x4 = *(const float4*)(in + base);
  float v[4] = {x4.x, x4.y, x4.z, x4.w};
  if constexpr (MODE == 2){
    float4 s4 = *(const float4*)(add + (row >> 11) * 1280 + lane * 4); // t_shift
    v[0] += s4.x; v[1] += s4.y; v[2] += s4.z; v[3] += s4.w;
  }
  float s = v[0] + v[1] + v[2] + v[3];
  #pragma unroll
  for (int d = 1; d < 64; d <<= 1) s += __shfl_xor(s, d);
  const float mean = s * (1.f / 256.f);
  float q = 0.f;
  #pragma unroll
  for (int i = 0; i < 4; ++i){ float dd = v[i] - mean; q += dd * dd; }
  #pragma unroll
  for (int d = 1; d < 64; d <<= 1) q += __shfl_xor(q, d);
  const float rstd = rsqrtf(q * (1.f / 256.f) + 1e-5f);
  float4 g4 = *(const float4*)(g + lane * 4);
  float4 b4 = *(const float4*)(bvec + lane * 4);
  float gv[4] = {g4.x, g4.y, g4.z, g4.w}, bb[4] = {b4.x, b4.y, b4.z, b4.w};
  float pe[4] = {0.f, 0.f, 0.f, 0.f};
  if constexpr (MODE == 0){
    float4 pp = *(const float4*)(add + (long)(row & (L_ - 1)) * 256 + lane * 4);
    pe[0] = pp.x; pe[1] = pp.y; pe[2] = pp.z; pe[3] = pp.w;
  }
  ushort4 o;
  u16 tmp[4];
  #pragma unroll
  for (int i = 0; i < 4; ++i){
    float y = (v[i] - mean) * rstd * gv[i] + bb[i] + pe[i];
    y = y * sigm(y);
    tmp[i] = f2bf(y);
  }
  o.x = tmp[0]; o.y = tmp[1]; o.z = tmp[2]; o.w = tmp[3];
  *(ushort4*)(out + base) = o;
}

// ---------- MFMA GEMM: C = A(MxK,bf16) * BT(NxK,bf16)^T + bias, fused epilogues ----------
// BM 128: 4 waves 2x2 (acc 4x4). BM 64: 4 waves 1x4 (acc 4x2) -> 2x blocks for N=256 GEMMs.
// EPI 0: bf16 out   1: f32 out   2: f32 out + res   3: split kv (k cols<256, v rest)
// EPI 4: FF1 gate: bf16 silu(v * sigmoid(t_scale[b][col]))   5: bf16 out * qk-scale (Q proj)
template<int BM, int EPI>
__global__ __launch_bounds__(256)
void gemm_bf(const u16* __restrict__ A, const u16* __restrict__ BT,
             const float* __restrict__ bias, const float* __restrict__ res,
             const float* __restrict__ thv,
             float* __restrict__ outF, u16* __restrict__ outB, u16* __restrict__ outB2,
             int M, int N, int K){
  constexpr int WM = BM / 64;          // 2 or 1
  constexpr int WN = 4 / WM;           // 2 or 4
  constexpr int NR = 8 / WN;           // 4 or 2
  __shared__ u16 As[BM * 64];
  __shared__ u16 Bs[128 * 64];
  const int t = threadIdx.x, lane = t & 63;
  const int lr = lane & 15, lg = lane >> 4;
  const int wv = t >> 6;
  const int wr = (wv / WN) * 64;
  const int wc = (wv % WN) * (NR * 16);
  const long bm = (long)blockIdx.x * BM, bn = (long)blockIdx.y * 128;
  const f32x4 zero = {0.f, 0.f, 0.f, 0.f};
  f32x4 acc[4][NR];
  #pragma unroll
  for (int m = 0; m < 4; ++m)
    #pragma unroll
    for (int n = 0; n < NR; ++n) acc[m][n] = zero;

  for (int kt = 0; kt < K; kt += 64){
    #pragma unroll
    for (int i = 0; i < BM/32; ++i){
      int o   = t * 16 + i * 4096;
      int row = o >> 7, cb = o & 127;
      int scb = cb ^ ((row & 7) << 4);
      gload16(&A[(bm + row) * K + kt + (scb >> 1)], &As[o >> 1]);
    }
    #pragma unroll
    for (int i = 0; i < 4; ++i){
      int o   = t * 16 + i * 4096;
      int row = o >> 7, cb = o & 127;
      int scb = cb ^ ((row & 7) << 4);
      gload16(&BT[(bn + row) * K + kt + (scb >> 1)], &Bs[o >> 1]);
    }
    __syncthreads();
    #pragma unroll
    for (int ks = 0; ks < 2; ++ks){
      bf16x8 av[4], bv[NR];
      const int cb = (ks * 32 + lg * 8) * 2;
      #pragma unroll
      for (int m = 0; m < 4; ++m){
        int row = wr + m * 16 + lr;
        av[m] = *(const bf16x8*)((const char*)As + row * 128 + (cb ^ ((row & 7) << 4)));
      }
      #pragma unroll
      for (int n = 0; n < NR; ++n){
        int row = wc + n * 16 + lr;
        bv[n] = *(const bf16x8*)((const char*)Bs + row * 128 + (cb ^ ((row & 7) << 4)));
      }
      #pragma unroll
      for (int m = 0; m < 4; ++m)
        #pragma unroll
        for (int n = 0; n < NR; ++n)
          acc[m][n] = mfma16(av[m], bv[n], acc[m][n]);
    }
    __syncthreads();
  }
  constexpr float QSC = 0.17677669529663687f * 1.4426950408889634f; // 1/sqrt(32)*log2e
  #pragma unroll
  for (int m = 0; m < 4; ++m)
    #pragma unroll
    for (int n = 0; n < NR; ++n)
      #pragma unroll
      for (int r = 0; r < 4; ++r){
        long row = bm + wr + m * 16 + lg * 4 + r;
        long col = bn + wc + n * 16 + lr;
        float v = acc[m][n][r] + bias[col];
        if constexpr (EPI == 0){
          outB[row * N + col] = f2bf(v);
        } else if constexpr (EPI == 1){
          outF[row * N + col] = v;
        } else if constexpr (EPI == 2){
          outF[row * N + col] = v + res[row * N + col];
        } else if constexpr (EPI == 3){
          if (col < 256) outB [row * 256  + col]        = f2bf(v);
          else           outB2[row * 2048 + (col - 256)] = f2bf(v);
        } else if constexpr (EPI == 4){
          int b = (int)(row >> 11);
          float ts = thv[b * 1280 + 256 + (int)col];
          float z = v * sigm(ts);
          outB[row * N + col] = f2bf(z * sigm(z));
        } else {
          outB[row * N + col] = f2bf(v * QSC);
        }
      }
}

// ---------- V transpose: (B*L, 2048 h-major) -> VT[bh][d][m] ----------
__global__ __launch_bounds__(256)
void vtrans(const u16* __restrict__ V, u16* __restrict__ VT){
  __shared__ u16 tile[64][72];
  int m0 = blockIdx.x * 64, d0 = blockIdx.y * 64;
  int bh = blockIdx.z, b = bh >> 3, h = bh & 7;
  int t = threadIdx.x;
  int rl = t >> 3, c8 = (t & 7) * 8;
  #pragma unroll
  for (int rep = 0; rep < 2; ++rep){
    int m = rl + rep * 32;
    uint4 x = *(const uint4*)(V + ((long)(b * L_ + m0 + m)) * 2048 + h * 256 + d0 + c8);
    *(uint4*)&tile[m][c8] = x;
  }
  __syncthreads();
  u16 tmp[8] __attribute__((aligned(16)));
  #pragma unroll
  for (int rep = 0; rep < 2; ++rep){
    int d = rl + rep * 32;
    #pragma unroll
    for (int i = 0; i < 8; ++i) tmp[i] = tile[c8 + i][d];
    *(uint4*)(VT + ((long)(bh * 256 + d0 + d)) * 2048 + m0 + c8) = *(uint4*)tmp;
  }
}

// ---------- flash attention v6 ----------
// 256 uniform blocks (1/CU): block (bh,p) does chunks p then 15-p (34 tiles total).
// 3-deep V/K pipeline: global_load_lds + counted vmcnt(9) + raw s_barrier (T3/T4).
// Swapped QK^T (mfma(K,Q)): lane owns a q-row -> lane-local max/sum (+2 shfl).
// Q pre-scaled by 1/sqrt(32)*log2e in its GEMM epilogue (exp2 domain).
__global__ __launch_bounds__(256, 1)
void attn6(const u16* __restrict__ Q, const u16* __restrict__ Kb,
           const u16* __restrict__ VT, u16* __restrict__ attout){
  const int bh = blockIdx.x, b = bh >> 3, h = bh & 7;
  const int p  = blockIdx.y;                 // 0..7
  const int t  = threadIdx.x;
  const int w  = t >> 6, lane = t & 63, lr = lane & 15, lg = lane >> 4;

  __shared__ u16 Vs[3][256 * 64];   // [d][m] 128B rows, XOR (d&7)<<4 byte swizzle (96KB)
  __shared__ u16 Ks[3][64 * 32];    // [m][dh] 64B rows, chunk XOR (m&3) swizzle   (12KB)
  __shared__ u16 Ps[4][32 * 64];    // per-wave P [q][m], XOR (q&7)<<3 elem swizzle(16KB)
  u16* myP = &Ps[w][0];

  const f32x4 zero = {0.f, 0.f, 0.f, 0.f};
  const u16* vbase = VT + (long)bh * 256 * 2048;
  const u16* kbase = Kb + (long)(b * L_) * 256 + h * 32;

  auto stV = [&](int m0, int buf){
    #pragma unroll
    for (int i = 0; i < 8; ++i){
      int ob = t * 16 + i * 4096;
      int d = ob >> 7, cb = ob & 127;
      int scb = cb ^ ((d & 7) << 4);
      gload16(vbase + (long)d * 2048 + m0 + (scb >> 1), &Vs[buf][ob >> 1]);
    }
  };
  auto stK = [&](int m0, int buf){
    int row = t >> 2, g = t & 3;
    gload16(kbase + (long)(m0 + row) * 256 + ((g ^ (row & 3)) << 3), &Ks[buf][t * 8]);
  };

  for (int half = 0; half < 2; ++half){
    const int chunk = half ? (15 - p) : p;
    const int n0 = chunk * 128;
    const int n_lo = n0 + w * 32;
    const int nt = (L_ - n0) >> 6;           // >= 2 always

    bf16x8 qf[2];
    #pragma unroll
    for (int qh = 0; qh < 2; ++qh)
      qf[qh] = *(const bf16x8*)(Q + ((long)(b * L_ + n_lo + qh * 16 + lr)) * 256 + h * 32 + lg * 8);

    f32x4 o[2][16];
    #pragma unroll
    for (int qh = 0; qh < 2; ++qh)
      #pragma unroll
      for (int c2 = 0; c2 < 16; ++c2) o[qh][c2] = zero;
    float mrun[2] = {-1e30f, -1e30f}, srun[2] = {0.f, 0.f};

    // prologue: stage tiles 0 and 1
    stV(n0, 0);      stK(n0, 0);
    stV(n0 + 64, 1); stK(n0 + 64, 1);

    int bufc = 0;
    for (int tt = 0; tt < nt; ++tt){
      const int m0 = n0 + tt * 64;
      if (tt + 1 < nt) WAITV(9); else WAITV(0);   // tile tt's 9 ops (V8+K1) complete
      __builtin_amdgcn_s_barrier();
      __builtin_amdgcn_sched_barrier(0);
      if (tt + 2 < nt){
        int nb = bufc + 2; if (nb >= 3) nb -= 3;
        stV(m0 + 128, nb); stK(m0 + 128, nb);     // overwrites buffer freed by tile tt-1
      }

      if (m0 + 64 > n_lo){
        const bool partial = (m0 < n_lo + 32);

        bf16x8 kf[4];
        #pragma unroll
        for (int c = 0; c < 4; ++c){
          int row = c * 16 + lr;
          kf[c] = *(const bf16x8*)&Ks[bufc][row * 32 + ((lg ^ (row & 3)) << 3)];
        }
        // swapped: S[m][q]; lane holds q = n_lo+qh*16+lr, m = m0+c*16+lg*4+r
        f32x4 sc2[2][4];
        #pragma unroll
        for (int qh = 0; qh < 2; ++qh)
          #pragma unroll
          for (int c = 0; c < 4; ++c)
            sc2[qh][c] = mfma16(kf[c], qf[qh], zero);

        if (partial){
          #pragma unroll
          for (int qh = 0; qh < 2; ++qh)
            #pragma unroll
            for (int c = 0; c < 4; ++c)
              #pragma unroll
              for (int r = 0; r < 4; ++r)
                if ((m0 + c * 16 + lg * 4 + r) < (n_lo + qh * 16 + lr)) sc2[qh][c][r] = -1e30f;
        }

        float tmax[2]; bool needl = false;
        #pragma unroll
        for (int qh = 0; qh < 2; ++qh){
          float t0 = fmaxf(fmaxf(sc2[qh][0][0], sc2[qh][0][1]), fmaxf(sc2[qh][0][2], sc2[qh][0][3]));
          #pragma unroll
          for (int c = 1; c < 4; ++c)
            t0 = fmaxf(t0, fmaxf(fmaxf(sc2[qh][c][0], sc2[qh][c][1]),
                                 fmaxf(sc2[qh][c][2], sc2[qh][c][3])));
          t0 = fmaxf(t0, __shfl_xor(t0, 16));
          t0 = fmaxf(t0, __shfl_xor(t0, 32));
          tmax[qh] = t0;
          needl |= (t0 > mrun[qh] + 11.5f);
        }
        if (__any(needl)){
          #pragma unroll
          for (int qh = 0; qh < 2; ++qh){
            float mn  = fmaxf(mrun[qh], tmax[qh]);
            float frc = exp2f(mrun[qh] - mn);
            mrun[qh] = mn; srun[qh] *= frc;
            float f0 = __shfl(frc, lg * 4 + 0), f1 = __shfl(frc, lg * 4 + 1);
            float f2 = __shfl(frc, lg * 4 + 2), f3 = __shfl(frc, lg * 4 + 3);
            f32x4 fv = {f0, f1, f2, f3};
            #pragma unroll
            for (int c2 = 0; c2 < 16; ++c2) o[qh][c2] *= fv;
          }
        }

        #pragma unroll
        for (int qh = 0; qh < 2; ++qh){
          const int q = qh * 16 + lr;
          const int sw = (q & 7) << 3;
          float rs = 0.f;
          #pragma unroll
          for (int c = 0; c < 4; ++c){
            float e0 = exp2f(sc2[qh][c][0] - mrun[qh]);
            float e1 = exp2f(sc2[qh][c][1] - mrun[qh]);
            float e2 = exp2f(sc2[qh][c][2] - mrun[qh]);
            float e3 = exp2f(sc2[qh][c][3] - mrun[qh]);
            if (partial && mrun[qh] < -1e29f){ e0 = e1 = e2 = e3 = 0.f; }
            rs += (e0 + e1) + (e2 + e3);
            ushort4 pk;
            pk.x = __builtin_bit_cast(u16, (__bf16)e0);
            pk.y = __builtin_bit_cast(u16, (__bf16)e1);
            pk.z = __builtin_bit_cast(u16, (__bf16)e2);
            pk.w = __builtin_bit_cast(u16, (__bf16)e3);
            *(ushort4*)&myP[q * 64 + ((c * 16 + lg * 4) ^ sw)] = pk;
          }
          rs += __shfl_xor(rs, 16);
          rs += __shfl_xor(rs, 32);
          srun[qh] += rs;
        }

        // ---- PV ----
        #pragma unroll
        for (int ks = 0; ks < 2; ++ks){
          bf16x8 pa[2];
          #pragma unroll
          for (int qh = 0; qh < 2; ++qh){
            const int q = qh * 16 + lr;
            pa[qh] = *(const bf16x8*)&myP[q * 64 + ((ks * 32 + lg * 8) ^ ((q & 7) << 3))];
          }
          #pragma unroll
          for (int c2 = 0; c2 < 16; ++c2){
            const int d = c2 * 16 + lr;
            bf16x8 vf = *(const bf16x8*)((const char*)&Vs[bufc][0] + d * 128 +
                                         ((ks * 64 + lg * 16) ^ ((d & 7) << 4)));
            #pragma unroll
            for (int qh = 0; qh < 2; ++qh)
              o[qh][c2] = mfma16(pa[qh], vf, o[qh][c2]);
          }
        }
      }
      bufc = (bufc + 1 == 3) ? 0 : bufc + 1;
    }

    // epilogue (srun/mrun live in column layout: redistribute via shfl)
    #pragma unroll
    for (int qh = 0; qh < 2; ++qh){
      float invc = 1.f / srun[qh];
      #pragma unroll
      for (int r = 0; r < 4; ++r){
        float inv = __shfl(invc, lg * 4 + r);
        long row = (long)(b * L_ + n_lo + qh * 16 + lg * 4 + r);
        #pragma unroll
        for (int c2 = 0; c2 < 16; ++c2)
          attout[row * 2048 + h * 256 + c2 * 16 + lr] = f2bf(o[qh][c2][r] * inv);
      }
    }
    __syncthreads();   // buffers reused by next half
  }
}

// ---------- tiny t-MLP ----------
__global__ __launch_bounds__(256)
void tmlp1(const float* __restrict__ t, const float* __restrict__ W,
           const float* __restrict__ bias, float* __restrict__ u){
  __shared__ float ts[256];
  int b = blockIdx.x, j = threadIdx.x;
  ts[j] = t[b * 256 + j];
  __syncthreads();
  float acc = bias[j];
  for (int k = 0; k < 256; ++k) acc += ts[k] * W[k * 256 + j];
  u[b * 256 + j] = acc * sigm(acc);
}
__global__ __launch_bounds__(256)
void tmlp2(const float* __restrict__ u, const float* __restrict__ W,
           const float* __restrict__ bias, float* __restrict__ th){
  __shared__ float us[256];
  int b = blockIdx.y, j = blockIdx.x * 256 + threadIdx.x;
  us[threadIdx.x] = u[b * 256 + threadIdx.x];
  __syncthreads();
  float acc = bias[j];
  for (int k = 0; k < 256; ++k) acc += us[k] * W[k * 1280 + j];
  th[b * 1280 + j] = acc;
}

extern "C" void kernel_launch(void* const* d_in, const int* in_sizes, int n_in,
                              void* d_out, int out_size, void* d_ws, size_t ws_size,
                              hipStream_t stream){
  (void)in_sizes; (void)n_in; (void)out_size; (void)ws_size;
  const float* x    = (const float*)d_in[0];
  const float* ctx  = (const float*)d_in[1];
  const float* tin  = (const float*)d_in[2];
  const float* pos  = (const float*)d_in[3];
  const float* ln_g = (const float*)d_in[4];
  const float* ln_b = (const float*)d_in[5];
  const float* Wq   = (const float*)d_in[6];
  const float* bq   = (const float*)d_in[7];
  const float* Wkv1 = (const float*)d_in[8];
  const float* bkv1 = (const float*)d_in[9];
  const float* kvg  = (const float*)d_in[10];
  const float* kvb  = (const float*)d_in[11];
  const float* Wkv2 = (const float*)d_in[12];
  const float* bkv2 = (const float*)d_in[13];
  const float* Wm   = (const float*)d_in[14];
  const float* bm   = (const float*)d_in[15];
  const float* Wt1  = (const float*)d_in[16];
  const float* bt1  = (const float*)d_in[17];
  const float* Wt2  = (const float*)d_in[18];
  const float* bt2  = (const float*)d_in[19];
  const float* fg   = (const float*)d_in[20];
  const float* fb   = (const float*)d_in[21];
  const float* Wff1 = (const float*)d_in[22];
  const float* bff1 = (const float*)d_in[23];
  const float* Wff2 = (const float*)d_in[24];
  const float* bff2 = (const float*)d_in[25];

  char* ws = (char*)d_ws;
  u16*   wt_q   = (u16*)  (ws + 0);
  u16*   wt_kv1 = (u16*)  (ws + 131072);
  u16*   wt_kv2 = (u16*)  (ws + 262144);
  u16*   wt_m   = (u16*)  (ws + 1441792);
  u16*   wt_ff1 = (u16*)  (ws + 2490368);
  u16*   wt_ff2 = (u16*)  (ws + 3014656);
  u16*   ctx_bf = (u16*)  (ws + 3538944);    // later reused: ff1 input
  u16*   qin_bf = (u16*)  (ws + 7733248);    // later reused: kvln
  u16*   q_bf   = (u16*)  (ws + 11927552);
  float* kv1    = (float*)(ws + 16121856);   // later reused: x2
  u16*   k_bf   = (u16*)  (ws + 24510464);
  u16*   v_bf   = (u16*)  (ws + 28704768);   // later reused: attention out
  u16*   vT     = (u16*)  (ws + 62259200);   // later reused: gated h
  float* ub     = (float*)(ws + 95813632);
  float* th     = (float*)(ws + 95817728);

  // weight prep (bf16, transposed to [N][K])
  wtrans<<<dim3(8, 8),  256, 0, stream>>>(Wq,   wt_q,   256,  256);
  wtrans<<<dim3(8, 8),  256, 0, stream>>>(Wkv1, wt_kv1, 256,  256);
  wtrans<<<dim3(72, 8), 256, 0, stream>>>(Wkv2, wt_kv2, 256,  2304);
  wtrans<<<dim3(8, 64), 256, 0, stream>>>(Wm,   wt_m,   2048, 256);
  wtrans<<<dim3(32, 8), 256, 0, stream>>>(Wff1, wt_ff1, 256,  1024);
  wtrans<<<dim3(8, 32), 256, 0, stream>>>(Wff2, wt_ff2, 1024, 256);
  cvt_bf<<<2048, 256, 0, stream>>>(ctx, ctx_bf);

  // q = silu(LN(x)+pos) @ Wq + bq   (epilogue folds 1/sqrt(32)*log2e into Q)
  ln_silu<0><<<2048, 256, 0, stream>>>(x, pos, ln_g, ln_b, qin_bf);
  gemm_bf<64,5><<<dim3(128, 2), 256, 0, stream>>>(qin_bf, wt_q, bq, nullptr, nullptr,
                                                  nullptr, q_bf, nullptr, 8192, 256, 256);
  // kv = silu(LN(ctx@Wkv1+bkv1)) @ Wkv2 + bkv2 -> K, V
  gemm_bf<64,1><<<dim3(128, 2), 256, 0, stream>>>(ctx_bf, wt_kv1, bkv1, nullptr, nullptr,
                                                  kv1, nullptr, nullptr, 8192, 256, 256);
  ln_silu<1><<<2048, 256, 0, stream>>>(kv1, nullptr, kvg, kvb, qin_bf);
  gemm_bf<128,3><<<dim3(64, 18), 256, 0, stream>>>(qin_bf, wt_kv2, bkv2, nullptr, nullptr,
                                                   nullptr, k_bf, v_bf, 8192, 2304, 256);
  vtrans<<<dim3(32, 4, 32), 256, 0, stream>>>(v_bf, vT);

  // attention (writes into v_bf region, reads vT/k_bf/q_bf)
  attn6<<<dim3(32, 8), 256, 0, stream>>>(q_bf, k_bf, vT, v_bf);

  // x2 = x + att @ Wm + bm
  gemm_bf<64,2><<<dim3(128, 2), 256, 0, stream>>>(v_bf, wt_m, bm, x, nullptr,
                                                  kv1, nullptr, nullptr, 8192, 256, 2048);
  // t-MLP
  tmlp1<<<4, 256, 0, stream>>>(tin, Wt1, bt1, ub);
  tmlp2<<<dim3(5, 4), 256, 0, stream>>>(ub, Wt2, bt2, th);
  // h = silu(LN(x2+shift)); hg = silu(h@Wff1+bff1 * sigmoid(scale)); out = hg@Wff2+bff2+x2
  ln_silu<2><<<2048, 256, 0, stream>>>(kv1, th, fg, fb, ctx_bf);
  gemm_bf<128,4><<<dim3(64, 8), 256, 0, stream>>>(ctx_bf, wt_ff1, bff1, nullptr, th,
                                                  nullptr, vT, nullptr, 8192, 1024, 256);
  gemm_bf<64,2><<<dim3(128, 2), 256, 0, stream>>>(vT, wt_ff2, bff2, kv1, nullptr,
                                                  (float*)d_out, nullptr, nullptr, 8192, 256, 1024);
}

// Round 6
// 247.730 us; speedup vs baseline: 1.5725x; 1.1094x over previous
//
#include <hip/hip_runtime.h>
#include <hip/hip_bf16.h>

#define DEVI __device__ __forceinline__
using u16 = unsigned short;
using u32 = unsigned int;

typedef __attribute__((ext_vector_type(4))) float f32x4;
typedef __attribute__((ext_vector_type(8))) __bf16 bf16x8;

constexpr int L_ = 2048;   // sequence length
// B=4, D=256, H=8, DH=32, DE=1024, M = B*L = 8192

DEVI u16 f2bf(float f){
  u32 u = __builtin_bit_cast(u32, f);
  u32 r = u + 0x7FFFu + ((u >> 16) & 1u);   // RNE
  return (u16)(r >> 16);
}
DEVI float sigm(float x){ return 1.f / (1.f + __expf(-x)); }

DEVI f32x4 mfma16(bf16x8 a, bf16x8 b, f32x4 c){
  return __builtin_amdgcn_mfma_f32_16x16x32_bf16(a, b, c, 0, 0, 0);
}

DEVI void gload16(const u16* src, u16* lds){
  __builtin_amdgcn_global_load_lds(
      (const __attribute__((address_space(1))) u32*)src,
      (__attribute__((address_space(3))) u32*)lds, 16, 0, 0);
}
DEVI void gload4(const u16* src, u16* lds){
  __builtin_amdgcn_global_load_lds(
      (const __attribute__((address_space(1))) u32*)src,
      (__attribute__((address_space(3))) u32*)lds, 4, 0, 0);
}

#define WAITV(N) asm volatile("s_waitcnt vmcnt(" #N ")" ::: "memory")

// ---------- weight f32 -> bf16, transposed to [N][K] ----------
__global__ __launch_bounds__(256)
void wtrans(const float* __restrict__ W, u16* __restrict__ WT, int K, int N){
  __shared__ float tile[32][33];
  int n0 = blockIdx.x * 32, k0 = blockIdx.y * 32;
  int tx = threadIdx.x & 31, ty = threadIdx.x >> 5;
  #pragma unroll
  for (int i = 0; i < 4; ++i){ int kk = ty + i*8; tile[kk][tx] = W[(long)(k0+kk)*N + n0 + tx]; }
  __syncthreads();
  #pragma unroll
  for (int i = 0; i < 4; ++i){ int nn = ty + i*8; WT[(long)(n0+nn)*K + k0 + tx] = f2bf(tile[tx][nn]); }
}

// ---------- f32 -> bf16 elementwise (context) ----------
__global__ __launch_bounds__(256)
void cvt_bf(const float* __restrict__ in, u16* __restrict__ out){
  long i = ((long)blockIdx.x * 256 + threadIdx.x) * 4;
  float4 v = *(const float4*)(in + i);
  ushort4 o; o.x = f2bf(v.x); o.y = f2bf(v.y); o.z = f2bf(v.z); o.w = f2bf(v.w);
  *(ushort4*)(out + i) = o;
}

// ---------- fused LayerNorm(+add)+SiLU -> bf16 ----------
// MODE 0: silu(LN(x)+pos[l])   MODE 1: silu(LN(x))   MODE 2: silu(LN(x+shift[b]))
template<int MODE>
__global__ __launch_bounds__(256)
void ln_silu(const float* __restrict__ in, const float* __restrict__ add,
             const float* __restrict__ g, const float* __restrict__ bvec,
             u16* __restrict__ out){
  const int row  = blockIdx.x * 4 + (threadIdx.x >> 6);
  const int lane = threadIdx.x & 63;
  const long base = (long)row * 256 + lane * 4;
  float4 x4 = *(const float4*)(in + base);
  float v[4] = {x4.x, x4.y, x4.z, x4.w};
  if constexpr (MODE == 2){
    float4 s4 = *(const float4*)(add + (row >> 11) * 1280 + lane * 4); // t_shift
    v[0] += s4.x; v[1] += s4.y; v[2] += s4.z; v[3] += s4.w;
  }
  float s = v[0] + v[1] + v[2] + v[3];
  #pragma unroll
  for (int d = 1; d < 64; d <<= 1) s += __shfl_xor(s, d);
  const float mean = s * (1.f / 256.f);
  float q = 0.f;
  #pragma unroll
  for (int i = 0; i < 4; ++i){ float dd = v[i] - mean; q += dd * dd; }
  #pragma unroll
  for (int d = 1; d < 64; d <<= 1) q += __shfl_xor(q, d);
  const float rstd = rsqrtf(q * (1.f / 256.f) + 1e-5f);
  float4 g4 = *(const float4*)(g + lane * 4);
  float4 b4 = *(const float4*)(bvec + lane * 4);
  float gv[4] = {g4.x, g4.y, g4.z, g4.w}, bb[4] = {b4.x, b4.y, b4.z, b4.w};
  float pe[4] = {0.f, 0.f, 0.f, 0.f};
  if constexpr (MODE == 0){
    float4 pp = *(const float4*)(add + (long)(row & (L_ - 1)) * 256 + lane * 4);
    pe[0] = pp.x; pe[1] = pp.y; pe[2] = pp.z; pe[3] = pp.w;
  }
  ushort4 o;
  u16 tmp[4];
  #pragma unroll
  for (int i = 0; i < 4; ++i){
    float y = (v[i] - mean) * rstd * gv[i] + bb[i] + pe[i];
    y = y * sigm(y);
    tmp[i] = f2bf(y);
  }
  o.x = tmp[0]; o.y = tmp[1]; o.z = tmp[2]; o.w = tmp[3];
  *(ushort4*)(out + base) = o;
}

// ---------- MFMA GEMM: C = A(MxK,bf16) * BT(NxK,bf16)^T + bias, fused epilogues ----------
// BM 128: 4 waves 2x2 (acc 4x4). BM 64: 4 waves 1x4 (acc 4x2) -> 2x blocks for N=256 GEMMs.
// EPI 0: bf16 out   1: f32 out   2: f32 out + res   3: split kv (k cols<256, v rest)
// EPI 4: FF1 gate: bf16 silu(v * sigmoid(t_scale[b][col]))   5: bf16 out * qk-scale (Q proj)
template<int BM, int EPI>
__global__ __launch_bounds__(256)
void gemm_bf(const u16* __restrict__ A, const u16* __restrict__ BT,
             const float* __restrict__ bias, const float* __restrict__ res,
             const float* __restrict__ thv,
             float* __restrict__ outF, u16* __restrict__ outB, u16* __restrict__ outB2,
             int M, int N, int K){
  constexpr int WM = BM / 64;          // 2 or 1
  constexpr int WN = 4 / WM;           // 2 or 4
  constexpr int NR = 8 / WN;           // 4 or 2
  __shared__ u16 As[BM * 64];
  __shared__ u16 Bs[128 * 64];
  const int t = threadIdx.x, lane = t & 63;
  const int lr = lane & 15, lg = lane >> 4;
  const int wv = t >> 6;
  const int wr = (wv / WN) * 64;
  const int wc = (wv % WN) * (NR * 16);
  const long bm = (long)blockIdx.x * BM, bn = (long)blockIdx.y * 128;
  const f32x4 zero = {0.f, 0.f, 0.f, 0.f};
  f32x4 acc[4][NR];
  #pragma unroll
  for (int m = 0; m < 4; ++m)
    #pragma unroll
    for (int n = 0; n < NR; ++n) acc[m][n] = zero;

  for (int kt = 0; kt < K; kt += 64){
    #pragma unroll
    for (int i = 0; i < BM/32; ++i){
      int o   = t * 16 + i * 4096;
      int row = o >> 7, cb = o & 127;
      int scb = cb ^ ((row & 7) << 4);
      gload16(&A[(bm + row) * K + kt + (scb >> 1)], &As[o >> 1]);
    }
    #pragma unroll
    for (int i = 0; i < 4; ++i){
      int o   = t * 16 + i * 4096;
      int row = o >> 7, cb = o & 127;
      int scb = cb ^ ((row & 7) << 4);
      gload16(&BT[(bn + row) * K + kt + (scb >> 1)], &Bs[o >> 1]);
    }
    __syncthreads();
    #pragma unroll
    for (int ks = 0; ks < 2; ++ks){
      bf16x8 av[4], bv[NR];
      const int cb = (ks * 32 + lg * 8) * 2;
      #pragma unroll
      for (int m = 0; m < 4; ++m){
        int row = wr + m * 16 + lr;
        av[m] = *(const bf16x8*)((const char*)As + row * 128 + (cb ^ ((row & 7) << 4)));
      }
      #pragma unroll
      for (int n = 0; n < NR; ++n){
        int row = wc + n * 16 + lr;
        bv[n] = *(const bf16x8*)((const char*)Bs + row * 128 + (cb ^ ((row & 7) << 4)));
      }
      #pragma unroll
      for (int m = 0; m < 4; ++m)
        #pragma unroll
        for (int n = 0; n < NR; ++n)
          acc[m][n] = mfma16(av[m], bv[n], acc[m][n]);
    }
    __syncthreads();
  }
  constexpr float QSC = 0.17677669529663687f * 1.4426950408889634f; // 1/sqrt(32)*log2e
  #pragma unroll
  for (int m = 0; m < 4; ++m)
    #pragma unroll
    for (int n = 0; n < NR; ++n)
      #pragma unroll
      for (int r = 0; r < 4; ++r){
        long row = bm + wr + m * 16 + lg * 4 + r;
        long col = bn + wc + n * 16 + lr;
        float v = acc[m][n][r] + bias[col];
        if constexpr (EPI == 0){
          outB[row * N + col] = f2bf(v);
        } else if constexpr (EPI == 1){
          outF[row * N + col] = v;
        } else if constexpr (EPI == 2){
          outF[row * N + col] = v + res[row * N + col];
        } else if constexpr (EPI == 3){
          if (col < 256) outB [row * 256  + col]        = f2bf(v);
          else           outB2[row * 2048 + (col - 256)] = f2bf(v);
        } else if constexpr (EPI == 4){
          int b = (int)(row >> 11);
          float ts = thv[b * 1280 + 256 + (int)col];
          float z = v * sigm(ts);
          outB[row * N + col] = f2bf(z * sigm(z));
        } else {
          outB[row * N + col] = f2bf(v * QSC);
        }
      }
}

// ---------- V transpose: (B*L, 2048 h-major) -> VT[bh][d][m] ----------
__global__ __launch_bounds__(256)
void vtrans(const u16* __restrict__ V, u16* __restrict__ VT){
  __shared__ u16 tile[64][72];
  int m0 = blockIdx.x * 64, d0 = blockIdx.y * 64;
  int bh = blockIdx.z, b = bh >> 3, h = bh & 7;
  int t = threadIdx.x;
  int rl = t >> 3, c8 = (t & 7) * 8;
  #pragma unroll
  for (int rep = 0; rep < 2; ++rep){
    int m = rl + rep * 32;
    uint4 x = *(const uint4*)(V + ((long)(b * L_ + m0 + m)) * 2048 + h * 256 + d0 + c8);
    *(uint4*)&tile[m][c8] = x;
  }
  __syncthreads();
  u16 tmp[8] __attribute__((aligned(16)));
  #pragma unroll
  for (int rep = 0; rep < 2; ++rep){
    int d = rl + rep * 32;
    #pragma unroll
    for (int i = 0; i < 8; ++i) tmp[i] = tile[c8 + i][d];
    *(uint4*)(VT + ((long)(bh * 256 + d0 + d)) * 2048 + m0 + c8) = *(uint4*)tmp;
  }
}

// ---------- flash attention v7: 8 waves x 16 q = 128 q/block, 2 waves/SIMD ----------
// 256 uniform blocks (1/CU): block (bh,p) does chunks p then 15-p (34 tiles).
// 3-deep V+K pipeline via global_load_lds + counted vmcnt(6) + raw s_barrier.
// Swapped QK^T (mfma(K,Q)); Q pre-scaled by 1/sqrt(32)*log2e (exp2 domain).
__global__ __launch_bounds__(512, 2)
void attn7(const u16* __restrict__ Q, const u16* __restrict__ Kb,
           const u16* __restrict__ VT, u16* __restrict__ attout){
  const int bh = blockIdx.x, b = bh >> 3, h = bh & 7;
  const int p  = blockIdx.y;                 // 0..7
  const int t  = threadIdx.x;
  const int w  = t >> 6, lane = t & 63, lr = lane & 15, lg = lane >> 4;

  __shared__ u16 Vs[3][256 * 64];   // [d][m] 128B rows, XOR (d&7)<<4 byte swizzle (96KB)
  __shared__ u16 Ks[3][64 * 32];    // [m][dh] 64B rows, 8-elem-block XOR (m&3)    (12KB)
  __shared__ u16 Ps[8][16 * 64];    // per-wave P [q][m], XOR (q&7)<<3 elem swizzle(16KB)
  u16* myP = &Ps[w][0];

  const f32x4 zero = {0.f, 0.f, 0.f, 0.f};
  const u16* vbase = VT + (long)bh * 256 * 2048;
  const u16* kbase = Kb + (long)(b * L_) * 256 + h * 32;

  // stage one 64-m tile: V (4 x gload16) + K (2 x gload4), 6 vmem ops/wave, dest lane-linear
  auto stage = [&](int m0, int buf){
    #pragma unroll
    for (int i = 0; i < 4; ++i){
      int ob = t * 16 + i * 8192;
      int d = ob >> 7, cb = ob & 127;
      int scb = cb ^ ((d & 7) << 4);
      gload16(vbase + (long)d * 2048 + m0 + (scb >> 1), &Vs[buf][ob >> 1]);
    }
    #pragma unroll
    for (int i = 0; i < 2; ++i){
      int g = t + i * 512;                 // 4B granule id, 1024 total
      int row = g >> 4, sl = g & 15;
      int scol = ((sl & 3) << 1) + ((((sl >> 2) ^ (row & 3))) << 3);
      gload4(kbase + (long)(m0 + row) * 256 + scol, &Ks[buf][g << 1]);
    }
  };

  for (int half = 0; half < 2; ++half){
    const int chunk = half ? (15 - p) : p;
    const int n0 = chunk * 128;
    const int n_lo = n0 + w * 16;            // this wave's 16 queries
    const int nt = (L_ - n0) >> 6;           // >= 2 always

    bf16x8 qf = *(const bf16x8*)(Q + ((long)(b * L_ + n_lo + lr)) * 256 + h * 32 + lg * 8);

    f32x4 o[16];
    #pragma unroll
    for (int c2 = 0; c2 < 16; ++c2) o[c2] = zero;
    float mrun = -1e30f, srun = 0.f;

    stage(n0, 0); stage(n0 + 64, 1);

    int bufc = 0;
    for (int tt = 0; tt < nt; ++tt){
      const int m0 = n0 + tt * 64;
      if (tt + 1 < nt) WAITV(6); else WAITV(0);   // tile tt's 6 ops complete
      __builtin_amdgcn_s_barrier();
      __builtin_amdgcn_sched_barrier(0);
      if (tt + 2 < nt){
        int nb = bufc + 2; if (nb >= 3) nb -= 3;
        stage(m0 + 128, nb);                      // buffer freed by tile tt-1
      }

      if (m0 + 64 > n_lo){
        const bool partial = (m0 < n_lo + 16);

        bf16x8 kf[4];
        #pragma unroll
        for (int c = 0; c < 4; ++c){
          int row = c * 16 + lr;
          kf[c] = *(const bf16x8*)&Ks[bufc][row * 32 + ((lg ^ (row & 3)) << 3)];
        }
        // swapped: S[m][q]; lane holds q = n_lo+lr, m = m0+c*16+lg*4+r
        f32x4 sc[4];
        #pragma unroll
        for (int c = 0; c < 4; ++c)
          sc[c] = mfma16(kf[c], qf, zero);

        if (partial){
          #pragma unroll
          for (int c = 0; c < 4; ++c)
            #pragma unroll
            for (int r = 0; r < 4; ++r)
              if ((m0 + c * 16 + lg * 4 + r) < (n_lo + lr)) sc[c][r] = -1e30f;
        }

        float t0 = fmaxf(fmaxf(sc[0][0], sc[0][1]), fmaxf(sc[0][2], sc[0][3]));
        #pragma unroll
        for (int c = 1; c < 4; ++c)
          t0 = fmaxf(t0, fmaxf(fmaxf(sc[c][0], sc[c][1]), fmaxf(sc[c][2], sc[c][3])));
        t0 = fmaxf(t0, __shfl_xor(t0, 16));
        t0 = fmaxf(t0, __shfl_xor(t0, 32));
        const bool needl = (t0 > mrun + 11.5f);
        if (__any(needl)){
          float mn  = fmaxf(mrun, t0);
          float frc = exp2f(mrun - mn);
          mrun = mn; srun *= frc;
          float f0 = __shfl(frc, lg * 4 + 0), f1 = __shfl(frc, lg * 4 + 1);
          float f2 = __shfl(frc, lg * 4 + 2), f3 = __shfl(frc, lg * 4 + 3);
          f32x4 fv = {f0, f1, f2, f3};
          #pragma unroll
          for (int c2 = 0; c2 < 16; ++c2) o[c2] *= fv;
        }

        // exp2 + row sum + P -> LDS (per-wave region, no barrier)
        {
          const int q = lr, sw = (q & 7) << 3;
          float rs = 0.f;
          #pragma unroll
          for (int c = 0; c < 4; ++c){
            float e0 = exp2f(sc[c][0] - mrun);
            float e1 = exp2f(sc[c][1] - mrun);
            float e2 = exp2f(sc[c][2] - mrun);
            float e3 = exp2f(sc[c][3] - mrun);
            if (partial && mrun < -1e29f){ e0 = e1 = e2 = e3 = 0.f; }
            rs += (e0 + e1) + (e2 + e3);
            ushort4 pk;
            pk.x = __builtin_bit_cast(u16, (__bf16)e0);
            pk.y = __builtin_bit_cast(u16, (__bf16)e1);
            pk.z = __builtin_bit_cast(u16, (__bf16)e2);
            pk.w = __builtin_bit_cast(u16, (__bf16)e3);
            *(ushort4*)&myP[q * 64 + ((c * 16 + lg * 4) ^ sw)] = pk;
          }
          rs += __shfl_xor(rs, 16);
          rs += __shfl_xor(rs, 32);
          srun += rs;
        }

        // ---- PV ----
        __builtin_amdgcn_s_setprio(1);
        #pragma unroll
        for (int ks = 0; ks < 2; ++ks){
          bf16x8 pa = *(const bf16x8*)&myP[lr * 64 + ((ks * 32 + lg * 8) ^ ((lr & 7) << 3))];
          #pragma unroll
          for (int c2 = 0; c2 < 16; ++c2){
            const int d = c2 * 16 + lr;
            bf16x8 vf = *(const bf16x8*)((const char*)&Vs[bufc][0] + d * 128 +
                                         ((ks * 64 + lg * 16) ^ ((d & 7) << 4)));
            o[c2] = mfma16(pa, vf, o[c2]);
          }
        }
        __builtin_amdgcn_s_setprio(0);
      }
      bufc = (bufc + 1 == 3) ? 0 : bufc + 1;
    }

    // epilogue (srun/mrun live at lane q=lr: redistribute via shfl)
    {
      float invc = 1.f / srun;
      #pragma unroll
      for (int r = 0; r < 4; ++r){
        float inv = __shfl(invc, lg * 4 + r);
        long row = (long)(b * L_ + n_lo + lg * 4 + r);
        #pragma unroll
        for (int c2 = 0; c2 < 16; ++c2)
          attout[row * 2048 + h * 256 + c2 * 16 + lr] = f2bf(o[c2][r] * inv);
      }
    }
    WAITV(0);          // drain epilogue stores so half-1's counted vmcnt is exact
    __syncthreads();   // buffers reused by next half
  }
}

// ---------- tiny t-MLP ----------
__global__ __launch_bounds__(256)
void tmlp1(const float* __restrict__ t, const float* __restrict__ W,
           const float* __restrict__ bias, float* __restrict__ u){
  __shared__ float ts[256];
  int b = blockIdx.x, j = threadIdx.x;
  ts[j] = t[b * 256 + j];
  __syncthreads();
  float acc = bias[j];
  for (int k = 0; k < 256; ++k) acc += ts[k] * W[k * 256 + j];
  u[b * 256 + j] = acc * sigm(acc);
}
__global__ __launch_bounds__(256)
void tmlp2(const float* __restrict__ u, const float* __restrict__ W,
           const float* __restrict__ bias, float* __restrict__ th){
  __shared__ float us[256];
  int b = blockIdx.y, j = blockIdx.x * 256 + threadIdx.x;
  us[threadIdx.x] = u[b * 256 + threadIdx.x];
  __syncthreads();
  float acc = bias[j];
  for (int k = 0; k < 256; ++k) acc += us[k] * W[k * 1280 + j];
  th[b * 1280 + j] = acc;
}

extern "C" void kernel_launch(void* const* d_in, const int* in_sizes, int n_in,
                              void* d_out, int out_size, void* d_ws, size_t ws_size,
                              hipStream_t stream){
  (void)in_sizes; (void)n_in; (void)out_size; (void)ws_size;
  const float* x    = (const float*)d_in[0];
  const float* ctx  = (const float*)d_in[1];
  const float* tin  = (const float*)d_in[2];
  const float* pos  = (const float*)d_in[3];
  const float* ln_g = (const float*)d_in[4];
  const float* ln_b = (const float*)d_in[5];
  const float* Wq   = (const float*)d_in[6];
  const float* bq   = (const float*)d_in[7];
  const float* Wkv1 = (const float*)d_in[8];
  const float* bkv1 = (const float*)d_in[9];
  const float* kvg  = (const float*)d_in[10];
  const float* kvb  = (const float*)d_in[11];
  const float* Wkv2 = (const float*)d_in[12];
  const float* bkv2 = (const float*)d_in[13];
  const float* Wm   = (const float*)d_in[14];
  const float* bm   = (const float*)d_in[15];
  const float* Wt1  = (const float*)d_in[16];
  const float* bt1  = (const float*)d_in[17];
  const float* Wt2  = (const float*)d_in[18];
  const float* bt2  = (const float*)d_in[19];
  const float* fg   = (const float*)d_in[20];
  const float* fb   = (const float*)d_in[21];
  const float* Wff1 = (const float*)d_in[22];
  const float* bff1 = (const float*)d_in[23];
  const float* Wff2 = (const float*)d_in[24];
  const float* bff2 = (const float*)d_in[25];

  char* ws = (char*)d_ws;
  u16*   wt_q   = (u16*)  (ws + 0);
  u16*   wt_kv1 = (u16*)  (ws + 131072);
  u16*   wt_kv2 = (u16*)  (ws + 262144);
  u16*   wt_m   = (u16*)  (ws + 1441792);
  u16*   wt_ff1 = (u16*)  (ws + 2490368);
  u16*   wt_ff2 = (u16*)  (ws + 3014656);
  u16*   ctx_bf = (u16*)  (ws + 3538944);    // later reused: ff1 input
  u16*   qin_bf = (u16*)  (ws + 7733248);    // later reused: kvln
  u16*   q_bf   = (u16*)  (ws + 11927552);
  float* kv1    = (float*)(ws + 16121856);   // later reused: x2
  u16*   k_bf   = (u16*)  (ws + 24510464);
  u16*   v_bf   = (u16*)  (ws + 28704768);   // later reused: attention out
  u16*   vT     = (u16*)  (ws + 62259200);   // later reused: gated h
  float* ub     = (float*)(ws + 95813632);
  float* th     = (float*)(ws + 95817728);

  // weight prep (bf16, transposed to [N][K])
  wtrans<<<dim3(8, 8),  256, 0, stream>>>(Wq,   wt_q,   256,  256);
  wtrans<<<dim3(8, 8),  256, 0, stream>>>(Wkv1, wt_kv1, 256,  256);
  wtrans<<<dim3(72, 8), 256, 0, stream>>>(Wkv2, wt_kv2, 256,  2304);
  wtrans<<<dim3(8, 64), 256, 0, stream>>>(Wm,   wt_m,   2048, 256);
  wtrans<<<dim3(32, 8), 256, 0, stream>>>(Wff1, wt_ff1, 256,  1024);
  wtrans<<<dim3(8, 32), 256, 0, stream>>>(Wff2, wt_ff2, 1024, 256);
  cvt_bf<<<2048, 256, 0, stream>>>(ctx, ctx_bf);

  // q = silu(LN(x)+pos) @ Wq + bq   (epilogue folds 1/sqrt(32)*log2e into Q)
  ln_silu<0><<<2048, 256, 0, stream>>>(x, pos, ln_g, ln_b, qin_bf);
  gemm_bf<64,5><<<dim3(128, 2), 256, 0, stream>>>(qin_bf, wt_q, bq, nullptr, nullptr,
                                                  nullptr, q_bf, nullptr, 8192, 256, 256);
  // kv = silu(LN(ctx@Wkv1+bkv1)) @ Wkv2 + bkv2 -> K, V
  gemm_bf<64,1><<<dim3(128, 2), 256, 0, stream>>>(ctx_bf, wt_kv1, bkv1, nullptr, nullptr,
                                                  kv1, nullptr, nullptr, 8192, 256, 256);
  ln_silu<1><<<2048, 256, 0, stream>>>(kv1, nullptr, kvg, kvb, qin_bf);
  gemm_bf<128,3><<<dim3(64, 18), 256, 0, stream>>>(qin_bf, wt_kv2, bkv2, nullptr, nullptr,
                                                   nullptr, k_bf, v_bf, 8192, 2304, 256);
  vtrans<<<dim3(32, 4, 32), 256, 0, stream>>>(v_bf, vT);

  // attention (writes into v_bf region, reads vT/k_bf/q_bf)
  attn7<<<dim3(32, 8), 512, 0, stream>>>(q_bf, k_bf, vT, v_bf);

  // x2 = x + att @ Wm + bm
  gemm_bf<64,2><<<dim3(128, 2), 256, 0, stream>>>(v_bf, wt_m, bm, x, nullptr,
                                                  kv1, nullptr, nullptr, 8192, 256, 2048);
  // t-MLP
  tmlp1<<<4, 256, 0, stream>>>(tin, Wt1, bt1, ub);
  tmlp2<<<dim3(5, 4), 256, 0, stream>>>(ub, Wt2, bt2, th);
  // h = silu(LN(x2+shift)); hg = silu(h@Wff1+bff1 * sigmoid(scale)); out = hg@Wff2+bff2+x2
  ln_silu<2><<<2048, 256, 0, stream>>>(kv1, th, fg, fb, ctx_bf);
  gemm_bf<128,4><<<dim3(64, 8), 256, 0, stream>>>(ctx_bf, wt_ff1, bff1, nullptr, th,
                                                  nullptr, vT, nullptr, 8192, 1024, 256);
  gemm_bf<64,2><<<dim3(128, 2), 256, 0, stream>>>(vT, wt_ff2, bff2, kv1, nullptr,
                                                  (float*)d_out, nullptr, nullptr, 8192, 256, 1024);
}